// Round 18
// baseline (1294.791 us; speedup 1.0000x reference)
//
#include <hip/hip_runtime.h>
#include <hip/hip_bf16.h>
#include <math.h>

#define Bb 1024
#define Tt 15
#define Ii 256
#define Hh 512
#define Ff 8
#define Gg 2048  // 4*Hh

typedef __attribute__((ext_vector_type(8))) short short8v;
typedef __attribute__((ext_vector_type(4))) float f32x4;

typedef const __attribute__((address_space(1))) void* gas_ptr;
typedef __attribute__((address_space(3))) void* las_ptr;

__device__ __forceinline__ float sigmoidf_(float x) {
    return __builtin_amdgcn_rcpf(1.0f + __expf(-x));
}
__device__ __forceinline__ float tanhf_(float x) {
    x = fminf(fmaxf(x, -15.0f), 15.0f);
    const float e = __expf(2.0f * x);
    return (e - 1.0f) * __builtin_amdgcn_rcpf(e + 1.0f);
}
__device__ __forceinline__ float bf2f(unsigned short u) {
    return __uint_as_float(((unsigned int)u) << 16);
}
__device__ __forceinline__ unsigned short f2bf(float f) {
    unsigned int u = __float_as_uint(f);
    u += 0x7fffu + ((u >> 16) & 1u);   // RNE
    return (unsigned short)(u >> 16);
}

// ---------------- fp32 -> bf16 conversion (n8 = n/8) ----------------
__global__ __launch_bounds__(256) void cvt_kernel(const float* __restrict__ in,
                                                  unsigned short* __restrict__ out, int n8) {
    const int i = blockIdx.x * 256 + threadIdx.x;
    if (i < n8) {
        const float4 v0 = ((const float4*)in)[i * 2];
        const float4 v1 = ((const float4*)in)[i * 2 + 1];
        union { unsigned short u[8]; short8v v; } ob;
        ob.u[0] = f2bf(v0.x); ob.u[1] = f2bf(v0.y); ob.u[2] = f2bf(v0.z); ob.u[3] = f2bf(v0.w);
        ob.u[4] = f2bf(v1.x); ob.u[5] = f2bf(v1.y); ob.u[6] = f2bf(v1.z); ob.u[7] = f2bf(v1.w);
        *(short8v*)&out[(size_t)i * 8] = ob.v;
    }
}

// ---------------- fp32 -> bf16 with gate-interleaved row permutation ----------------
// out[f][hb][r][K], r=0..127: gate=(r>>4)&3, hl=(r&15)+((r>>6)<<4); src row = gate*Hh+hb*32+hl.
// With this layout, MFMA D-fragment j holds gate j for the same (b,h) in every lane.
__global__ __launch_bounds__(256) void cvt_wperm_kernel(const float* __restrict__ in,
                                                        unsigned short* __restrict__ out,
                                                        int Kc, int nchunks) {
    const int i = blockIdx.x * 256 + threadIdx.x;
    if (i < nchunks) {
        const int k8 = i % Kc;
        const int r  = (i / Kc) & 127;
        const int hb = (i / (Kc * 128)) & 15;
        const int f  = i / (Kc * 128 * 16);
        const int gate = (r >> 4) & 3;
        const int hl = (r & 15) + ((r >> 6) << 4);
        const size_t src = ((size_t)f * Gg + gate * Hh + hb * 32 + hl) * (size_t)(Kc * 8) + k8 * 8;
        const float4 v0 = *(const float4*)(in + src);
        const float4 v1 = *(const float4*)(in + src + 4);
        union { unsigned short u[8]; short8v v; } ob;
        ob.u[0] = f2bf(v0.x); ob.u[1] = f2bf(v0.y); ob.u[2] = f2bf(v0.z); ob.u[3] = f2bf(v0.w);
        ob.u[4] = f2bf(v1.x); ob.u[5] = f2bf(v1.y); ob.u[6] = f2bf(v1.z); ob.u[7] = f2bf(v1.w);
        *(short8v*)&out[(size_t)i * 8] = ob.v;
    }
}

// ---------------- GEMM body: A LDS-dbuf + B LDS-single (49 KB -> 3 blocks/CU) ----------------
// MODE 0/1: LSTM step, N-tile = 32 h x 4 gates (gate-interleaved W rows). MODE 2: proj.
// Tile 128x128, 4 waves, BK=64. LDS: abuf0 16K | abuf1 16K | bbuf 16K. A prefetched one
// tile ahead (dbuf); B staged single-buffered right after the post-compute barrier.
// Hazards: stageA(it+1) writes abuf[(it+1)&1] after iter(it-1)'s trailing barrier (last
// readers' lgkm-complete before that barrier). stageB(it+1) issues after compute(it)+barrier.
// vmcnt(4) after stageA(it+1) leaves only its 4 ops outstanding -> A(it),B(it) complete
// BEFORE the publishing barrier (R12 lesson). Final tile: trailing barrier skipped
// (no further stageA/stageB; epilogues touch no staged LDS).
template<int MODE>
__device__ __forceinline__ void step_body(
    bool first, int f, int h0, int b0, int t, int hb, int bb,
    const short* ax, long axs, const short* ah, long ahs,
    const short* __restrict__ wxp, const short* __restrict__ whp,
    const float* __restrict__ bias, unsigned short* __restrict__ cbuf,
    unsigned short* __restrict__ ydst,
    float* __restrict__ part, char* smem)
{
    constexpr int KX = (MODE == 0) ? Ii : Hh;
    constexpr int NX = KX / 64;
    const int NT = (MODE == 2) ? NX : (first ? NX : NX + Hh / 64);

    const int tid = threadIdx.x;
    const int wave = tid >> 6, lane = tid & 63;
    const int wm = (wave >> 1) * 64, wn = (wave & 1) * 64;

    short* sStage = (short*)smem;             // abuf0[0,8192) abuf1[8192,16384) bbuf[16384,24576)
    float* pr = (float*)(smem + 49152);

    f32x4 acc[4][4];
#pragma unroll
    for (int i = 0; i < 4; ++i)
#pragma unroll
        for (int j = 0; j < 4; ++j) acc[i][j] = (f32x4){0.f, 0.f, 0.f, 0.f};

    // staging geometry: per gload_lds instr: 64 lanes x 16B = 1KB = 8 rows of 128B
    const int srow8 = lane >> 3;
    const int csrc  = (lane & 7) ^ srow8;          // pre-swizzled source chunk
    const int frow  = lane & 15, fks = lane >> 4;

    auto stageA = [&](int it, int buf) {
        const short* abase; long as; int kb;
        if (it < NX) { abase = ax; as = axs; kb = it * 64; }
        else         { abase = ah; as = ahs; kb = (it - NX) * 64; }
        short* dA = sStage + buf * 8192;
#pragma unroll
        for (int i = 0; i < 4; ++i) {
            const int inst = wave * 4 + i;
            const int row = inst * 8 + srow8;
            const short* srcA = abase + (size_t)row * as + kb + csrc * 8;
            __builtin_amdgcn_global_load_lds((gas_ptr)(const void*)srcA,
                (las_ptr)(void*)(dA + inst * 512), 16, 0, 0);
        }
    };

    auto stageB = [&](int it) {
        const short* wbase; int K; int kb;
        if (it < NX) { wbase = wxp; K = KX; kb = it * 64; }
        else         { wbase = whp; K = Hh; kb = (it - NX) * 64; }
        short* dB = sStage + 16384;
#pragma unroll
        for (int i = 0; i < 4; ++i) {
            const int inst = wave * 4 + i;
            const int row = inst * 8 + srow8;
            const short* srcB = wbase + (size_t)row * K + kb + csrc * 8;
            __builtin_amdgcn_global_load_lds((gas_ptr)(const void*)srcB,
                (las_ptr)(void*)(dB + inst * 512), 16, 0, 0);
        }
    };

    auto compute = [&](int abuf) {
        const short* bA = sStage + abuf * 8192;
        const short* bB = sStage + 16384;
        __builtin_amdgcn_s_setprio(1);
#pragma unroll
        for (int ks = 0; ks < 2; ++ks) {
            short8v av[4], bv[4];
#pragma unroll
            for (int i = 0; i < 4; ++i) {
                const int r = wm + i * 16 + frow;
                av[i] = *(const short8v*)&bA[r * 64 + (((fks + ks * 4) ^ (r & 7)) * 8)];
            }
#pragma unroll
            for (int j = 0; j < 4; ++j) {
                const int r = wn + j * 16 + frow;
                bv[j] = *(const short8v*)&bB[r * 64 + (((fks + ks * 4) ^ (r & 7)) * 8)];
            }
#pragma unroll
            for (int i = 0; i < 4; ++i)
#pragma unroll
                for (int j = 0; j < 4; ++j)
                    acc[i][j] = __builtin_amdgcn_mfma_f32_16x16x32_bf16(av[i], bv[j], acc[i][j], 0, 0, 0);
        }
        __builtin_amdgcn_s_setprio(0);
    };

    // per-lane output coords and bias (register-local epilogue)
    const int hoff = ((wn >> 6) << 4) + (lane & 15);   // MODE 0/1: h within 32-block
    float bi[4] = {0.f, 0.f, 0.f, 0.f};
    if constexpr (MODE != 2) {
#pragma unroll
        for (int g = 0; g < 4; ++g) bi[g] = bias[(size_t)f * Gg + g * Hh + h0 + hoff];
    } else {
#pragma unroll
        for (int j = 0; j < 4; ++j) bi[j] = bias[h0 + wn + j * 16 + (lane & 15)];
    }
    asm volatile("" : "+v"(bi[0]), "+v"(bi[1]), "+v"(bi[2]), "+v"(bi[3]));

    // -------- pipelined K loop: A 1-tile-ahead dbuf, B single-buf staged post-barrier --------
    stageA(0, 0);
    stageB(0);
    for (int it = 0; it < NT; ++it) {
        if (it + 1 < NT) {
            stageA(it + 1, (it + 1) & 1);
            asm volatile("s_waitcnt vmcnt(4)" ::: "memory");   // A(it), B(it) complete
        } else {
            asm volatile("s_waitcnt vmcnt(0)" ::: "memory");
        }
        __builtin_amdgcn_s_barrier();
        __builtin_amdgcn_sched_barrier(0);
        compute(it & 1);
        __builtin_amdgcn_sched_barrier(0);
        if (it + 1 < NT) {
            __builtin_amdgcn_s_barrier();
            stageB(it + 1);
        }
    }

    // ---- register-local epilogue: gates i,f,g,o live in acc[i][0..3][r] of this lane ----
    if constexpr (MODE != 2) {
#pragma unroll
        for (int i = 0; i < 4; ++i)
#pragma unroll
            for (int r = 0; r < 4; ++r) {
                const int b = b0 + wm + i * 16 + ((lane >> 4) << 2) + r;
                const float gi = acc[i][0][r] + bi[0];
                const float gf = acc[i][1][r] + bi[1];
                const float gg = acc[i][2][r] + bi[2];
                const float go = acc[i][3][r] + bi[3];
                const size_t cidx = ((size_t)f * Bb + b) * Hh + h0 + hoff;
                const float cold = first ? 0.f : bf2f(cbuf[cidx]);
                const float cn = sigmoidf_(gf) * cold + sigmoidf_(gi) * tanhf_(gg);
                const float hv = sigmoidf_(go) * tanhf_(cn);
                cbuf[cidx] = f2bf(cn);
                const unsigned short hb2 = f2bf(hv);
                if (MODE == 0)
                    ydst[(((size_t)f * Bb + b) * Tt + t) * Hh + h0 + hoff] = hb2;
                else
                    ydst[cidx] = hb2;
            }
    } else {
        float ssum = 0.f, ssq = 0.f;
#pragma unroll
        for (int i = 0; i < 4; ++i)
#pragma unroll
            for (int r = 0; r < 4; ++r) {
                const int b = b0 + wm + i * 16 + ((lane >> 4) << 2) + r;
                unsigned short* dst = ydst + (((size_t)f * Bb + b) * Tt + t) * Hh;
#pragma unroll
                for (int j = 0; j < 4; ++j) {
                    const int o = h0 + wn + j * 16 + (lane & 15);
                    const unsigned short hb2 = f2bf(acc[i][j][r] + bi[j]);
                    const float hv = bf2f(hb2);
                    ssum += hv; ssq += hv * hv;
                    dst[o] = hb2;
                }
            }
#pragma unroll
        for (int off2 = 32; off2 > 0; off2 >>= 1) {
            ssum += __shfl_down(ssum, off2);
            ssq  += __shfl_down(ssq,  off2);
        }
        if (lane == 0) { pr[wave * 2] = ssum; pr[wave * 2 + 1] = ssq; }
        __syncthreads();
        if (tid == 0) {
            float S = 0.f, Q = 0.f;
#pragma unroll
            for (int w = 0; w < 4; ++w) { S += pr[w * 2]; Q += pr[w * 2 + 1]; }
            const size_t pi = (((size_t)f * Tt + t) * 4 + hb) * 8 + bb;
            part[pi * 2] = S; part[pi * 2 + 1] = Q;
        }
    }
}

// ---------------- merged per-step kernel: L0(t=d) | L1(t=d-1) | proj(t=d-2) ----------------
// grid = (144, 16): blockIdx.x = zz*8 + f. Role selector zz in the HIGH bits of x so
// dispatch order interleaves L0/L1/proj every 8 blocks (decorrelated pipeline phases on
// each CU); f stays in the low 3 bits so linear%8 = f (gridX=144 = 0 mod 8) -> per-XCD
// weight residency preserved. All cross-role deps span a dispatch boundary -> race-free.
__global__ __launch_bounds__(256, 3) void step_merged(
    const short* __restrict__ Xbf, short* __restrict__ ybuf,
    short* __restrict__ h1A, short* __restrict__ h1B,
    const short* __restrict__ W0x, const short* __restrict__ W0h,
    const short* __restrict__ W1x, const short* __restrict__ W1h,
    const short* __restrict__ A1bf,
    const float* __restrict__ b0p, const float* __restrict__ b1p,
    const float* __restrict__ c1v,
    unsigned short* __restrict__ c0buf, unsigned short* __restrict__ c1buf,
    float* __restrict__ part, int d)
{
    __shared__ __align__(16) char smem[49152 + 64];
    const int f  = blockIdx.x & 7;
    const int zz = blockIdx.x >> 3;

    if (zz < 8) {                       // ---- layer 0, t = d ----
        const int t = d;
        if (t >= Tt) return;
        const int hb = blockIdx.y, h0 = hb * 32, b0 = zz * 128;
        const bool first = (t == 0);
        const short* ax = Xbf + ((size_t)b0 * Tt + t) * Ii;
        const short* ah = first ? nullptr
                                : ybuf + (((size_t)f * Bb + b0) * Tt + (t - 1)) * Hh;
        step_body<0>(first, f, h0, b0, t, hb, zz,
                     ax, (long)Tt * Ii, ah, (long)Tt * Hh,
                     W0x + ((size_t)f * 16 + hb) * 128 * Ii,
                     W0h + ((size_t)f * 16 + hb) * 128 * Hh,
                     b0p, c0buf, (unsigned short*)ybuf, part, smem);
    } else if (zz < 16) {               // ---- layer 1, t = d-1 ----
        const int t = d - 1;
        if (t < 0 || t >= Tt) return;
        const int bb = zz - 8;
        const int hb = blockIdx.y, h0 = hb * 32, b0 = bb * 128;
        const bool first = (t == 0);
        short* hn = (t & 1) ? h1A : h1B;
        const short* hp = (t & 1) ? h1B : h1A;
        const short* ax = ybuf + (((size_t)f * Bb + b0) * Tt + t) * Hh;
        const short* ah = first ? nullptr : hp + ((size_t)f * Bb + b0) * Hh;
        step_body<1>(first, f, h0, b0, t, hb, bb,
                     ax, (long)Tt * Hh, ah, (long)Hh,
                     W1x + ((size_t)f * 16 + hb) * 128 * Hh,
                     W1h + ((size_t)f * 16 + hb) * 128 * Hh,
                     b1p, c1buf, (unsigned short*)hn, part, smem);
    } else {                            // ---- proj, t = d-2 ----
        const int t = d - 2;
        if (t < 0) return;
        const int hb = blockIdx.y & 3, h0 = hb * 128;
        const int bb = (zz - 16) * 4 + (blockIdx.y >> 2), b0 = bb * 128;
        const short* hn = (t & 1) ? h1A : h1B;
        const short* ax = hn + ((size_t)f * Bb + b0) * Hh;
        step_body<2>(false, f, h0, b0, t, hb, bb,
                     ax, (long)Hh, nullptr, 0L,
                     A1bf + (size_t)h0 * Hh, nullptr,
                     c1v, nullptr, (unsigned short*)ybuf, part, smem);
    }
}

// ---------------- stats combine: mean / rsqrt(var) per (f,t) from 32 partials ----------------
__global__ void stats_combine_kernel(const float* __restrict__ part, float* __restrict__ stats)
{
    const int i = threadIdx.x;
    if (i < Ff * Tt) {
        float s = 0.f, q = 0.f;
        for (int j = 0; j < 32; ++j) { s += part[(i * 32 + j) * 2]; q += part[(i * 32 + j) * 2 + 1]; }
        const float n = (float)((size_t)Bb * Hh);
        const float mean = s / n;
        const float var  = q / n - mean * mean;
        stats[i * 2]     = mean;
        stats[i * 2 + 1] = rsqrtf(var + 1e-5f);
    }
}

// ---------------- Output: out[b,t,f] = sum_o relu(bn(htmp)) * A2[o] + c2 ----------------
__global__ __launch_bounds__(256) void out_kernel(
    const unsigned short* __restrict__ htmp, const float* __restrict__ stats,
    const float* __restrict__ gamma, const float* __restrict__ beta,
    const float* __restrict__ A2, const float* __restrict__ c2,
    float* __restrict__ out)
{
    const int wave = threadIdx.x >> 6;
    const int lane = threadIdx.x & 63;
    const size_t row = (size_t)blockIdx.x * 4 + wave;   // (f*B + b)*T + t
    const int t = (int)(row % Tt);
    const size_t fb = row / Tt;
    const int b = (int)(fb % Bb);
    const int f = (int)(fb / Bb);

    const float mean = stats[(f * Tt + t) * 2];
    const float inv  = stats[(f * Tt + t) * 2 + 1];
    const float ga = gamma[t], be = beta[t];
    const unsigned short* hrow = htmp + row * Hh;

    union { float4 f4; unsigned short u[8]; } hv;
    hv.f4 = *(const float4*)(hrow + lane * 8);
    const float4 a0 = *(const float4*)(A2 + lane * 8);
    const float4 a1 = *(const float4*)(A2 + lane * 8 + 4);
    const float a2v[8] = {a0.x, a0.y, a0.z, a0.w, a1.x, a1.y, a1.z, a1.w};

    float acc = 0.f;
#pragma unroll
    for (int j = 0; j < 8; ++j) {
        const float x = (bf2f(hv.u[j]) - mean) * inv * ga + be;
        acc += fmaxf(x, 0.f) * a2v[j];
    }
#pragma unroll
    for (int off = 32; off > 0; off >>= 1) acc += __shfl_down(acc, off);
    if (lane == 0) out[(size_t)b * Tt * Ff + (size_t)t * Ff + f] = acc + c2[0];
}

extern "C" void kernel_launch(void* const* d_in, const int* in_sizes, int n_in,
                              void* d_out, int out_size, void* d_ws, size_t ws_size,
                              hipStream_t stream) {
    const float* X     = (const float*)d_in[0];
    const float* Wih0  = (const float*)d_in[1];
    const float* Whh0  = (const float*)d_in[2];
    const float* b0p   = (const float*)d_in[3];
    const float* Wih1  = (const float*)d_in[4];
    const float* Whh1  = (const float*)d_in[5];
    const float* b1p   = (const float*)d_in[6];
    const float* A1    = (const float*)d_in[7];
    const float* c1v   = (const float*)d_in[8];
    const float* gamma = (const float*)d_in[9];
    const float* beta  = (const float*)d_in[10];
    const float* A2    = (const float*)d_in[11];
    const float* c2    = (const float*)d_in[12];
    float* out = (float*)d_out;

    // ---- workspace layout (bytes), total ~209 MiB ----
    char* ws = (char*)d_ws;
    size_t off = 0;
    short* Xbf    = (short*)(ws + off); off += (size_t)Bb * Tt * Ii * 2;
    short* Wih0bf = (short*)(ws + off); off += (size_t)Ff * Gg * Ii * 2;
    short* Whh0bf = (short*)(ws + off); off += (size_t)Ff * Gg * Hh * 2;
    short* Wih1bf = (short*)(ws + off); off += (size_t)Ff * Gg * Hh * 2;
    short* Whh1bf = (short*)(ws + off); off += (size_t)Ff * Gg * Hh * 2;
    short* A1bf   = (short*)(ws + off); off += (size_t)Hh * Hh * 2;
    short* ybuf   = (short*)(ws + off); off += (size_t)Ff * Bb * Tt * Hh * 2;
    short* h1A    = (short*)(ws + off); off += (size_t)Ff * Bb * Hh * 2;
    short* h1B    = (short*)(ws + off); off += (size_t)Ff * Bb * Hh * 2;
    unsigned short* c0buf = (unsigned short*)(ws + off); off += (size_t)Ff * Bb * Hh * 2;
    unsigned short* c1buf = (unsigned short*)(ws + off); off += (size_t)Ff * Bb * Hh * 2;
    float* part   = (float*)(ws + off); off += (size_t)Ff * Tt * 32 * 2 * 4;
    float* stats  = (float*)(ws + off); off += (size_t)Ff * Tt * 2 * 4;

    const dim3 blk(256);
    cvt_kernel<<<dim3((Bb * Tt * Ii / 8 + 255) / 256), blk, 0, stream>>>(X, (unsigned short*)Xbf, Bb * Tt * Ii / 8);
    // weights: gate-interleaved permuted layout [f][hb][128][K]
    cvt_wperm_kernel<<<dim3((Ff * Gg * Ii / 8 + 255) / 256), blk, 0, stream>>>(
        Wih0, (unsigned short*)Wih0bf, Ii / 8, Ff * Gg * Ii / 8);
    cvt_wperm_kernel<<<dim3((Ff * Gg * Hh / 8 + 255) / 256), blk, 0, stream>>>(
        Whh0, (unsigned short*)Whh0bf, Hh / 8, Ff * Gg * Hh / 8);
    cvt_wperm_kernel<<<dim3((Ff * Gg * Hh / 8 + 255) / 256), blk, 0, stream>>>(
        Wih1, (unsigned short*)Wih1bf, Hh / 8, Ff * Gg * Hh / 8);
    cvt_wperm_kernel<<<dim3((Ff * Gg * Hh / 8 + 255) / 256), blk, 0, stream>>>(
        Whh1, (unsigned short*)Whh1bf, Hh / 8, Ff * Gg * Hh / 8);
    cvt_kernel<<<dim3((Hh * Hh / 8 + 255) / 256), blk, 0, stream>>>(A1, (unsigned short*)A1bf, Hh * Hh / 8);

    // software-pipelined role-merged steps: d=0..16 (roles interleaved in dispatch order)
    const dim3 gmerged(144, 16, 1);
    for (int d = 0; d <= Tt + 1; ++d) {
        step_merged<<<gmerged, blk, 0, stream>>>(
            Xbf, ybuf, h1A, h1B,
            Wih0bf, Whh0bf, Wih1bf, Whh1bf, A1bf,
            b0p, b1p, c1v, c0buf, c1buf, part, d);
    }

    stats_combine_kernel<<<dim3(1), dim3(128), 0, stream>>>(part, stats);
    out_kernel<<<dim3(Ff * Bb * Tt / 4), blk, 0, stream>>>((const unsigned short*)ybuf, stats,
        gamma, beta, A2, c2, out);
    (void)in_sizes; (void)n_in; (void)out_size; (void)ws_size;
}

// Round 19
// 1235.377 us; speedup vs baseline: 1.0481x; 1.0481x over previous
//
#include <hip/hip_runtime.h>
#include <hip/hip_bf16.h>
#include <math.h>

#define Bb 1024
#define Tt 15
#define Ii 256
#define Hh 512
#define Ff 8
#define Gg 2048  // 4*Hh

typedef __attribute__((ext_vector_type(8))) short short8v;
typedef __attribute__((ext_vector_type(4))) float f32x4;

typedef const __attribute__((address_space(1))) void* gas_ptr;
typedef __attribute__((address_space(3))) void* las_ptr;

__device__ __forceinline__ float sigmoidf_(float x) {
    return __builtin_amdgcn_rcpf(1.0f + __expf(-x));
}
__device__ __forceinline__ float tanhf_(float x) {
    x = fminf(fmaxf(x, -15.0f), 15.0f);
    const float e = __expf(2.0f * x);
    return (e - 1.0f) * __builtin_amdgcn_rcpf(e + 1.0f);
}
__device__ __forceinline__ float bf2f(unsigned short u) {
    return __uint_as_float(((unsigned int)u) << 16);
}
__device__ __forceinline__ unsigned short f2bf(float f) {
    unsigned int u = __float_as_uint(f);
    u += 0x7fffu + ((u >> 16) & 1u);   // RNE
    return (unsigned short)(u >> 16);
}

// ---------------- fp32 -> bf16 conversion (n8 = n/8) ----------------
__global__ __launch_bounds__(256) void cvt_kernel(const float* __restrict__ in,
                                                  unsigned short* __restrict__ out, int n8) {
    const int i = blockIdx.x * 256 + threadIdx.x;
    if (i < n8) {
        const float4 v0 = ((const float4*)in)[i * 2];
        const float4 v1 = ((const float4*)in)[i * 2 + 1];
        union { unsigned short u[8]; short8v v; } ob;
        ob.u[0] = f2bf(v0.x); ob.u[1] = f2bf(v0.y); ob.u[2] = f2bf(v0.z); ob.u[3] = f2bf(v0.w);
        ob.u[4] = f2bf(v1.x); ob.u[5] = f2bf(v1.y); ob.u[6] = f2bf(v1.z); ob.u[7] = f2bf(v1.w);
        *(short8v*)&out[(size_t)i * 8] = ob.v;
    }
}

// ---------------- X: fp32 [b][t][i] -> bf16 [t][b][i] (time-major) ----------------
__global__ __launch_bounds__(256) void cvt_xT_kernel(const float* __restrict__ in,
                                                     unsigned short* __restrict__ out) {
    const int i = blockIdx.x * 256 + threadIdx.x;   // chunk id over Bb*Tt*(Ii/8)
    if (i < Bb * Tt * (Ii / 8)) {
        const int c = i % (Ii / 8);
        const int rest = i / (Ii / 8);
        const int t = rest % Tt;
        const int b = rest / Tt;
        const size_t src = ((size_t)(b * Tt + t) * (Ii / 8) + c) * 8;
        const float4 v0 = *(const float4*)(in + src);
        const float4 v1 = *(const float4*)(in + src + 4);
        union { unsigned short u[8]; short8v v; } ob;
        ob.u[0] = f2bf(v0.x); ob.u[1] = f2bf(v0.y); ob.u[2] = f2bf(v0.z); ob.u[3] = f2bf(v0.w);
        ob.u[4] = f2bf(v1.x); ob.u[5] = f2bf(v1.y); ob.u[6] = f2bf(v1.z); ob.u[7] = f2bf(v1.w);
        *(short8v*)&out[((size_t)(t * Bb + b) * (Ii / 8) + c) * 8] = ob.v;
    }
}

// ---------------- fp32 -> bf16 with gate-interleaved row permutation ----------------
// out[f][hb][r][K], r=0..127: gate=(r>>4)&3, hl=(r&15)+((r>>6)<<4); src row = gate*Hh+hb*32+hl.
// With this layout, MFMA D-fragment j holds gate j for the same (b,h) in every lane.
__global__ __launch_bounds__(256) void cvt_wperm_kernel(const float* __restrict__ in,
                                                        unsigned short* __restrict__ out,
                                                        int Kc, int nchunks) {
    const int i = blockIdx.x * 256 + threadIdx.x;
    if (i < nchunks) {
        const int k8 = i % Kc;
        const int r  = (i / Kc) & 127;
        const int hb = (i / (Kc * 128)) & 15;
        const int f  = i / (Kc * 128 * 16);
        const int gate = (r >> 4) & 3;
        const int hl = (r & 15) + ((r >> 6) << 4);
        const size_t src = ((size_t)f * Gg + gate * Hh + hb * 32 + hl) * (size_t)(Kc * 8) + k8 * 8;
        const float4 v0 = *(const float4*)(in + src);
        const float4 v1 = *(const float4*)(in + src + 4);
        union { unsigned short u[8]; short8v v; } ob;
        ob.u[0] = f2bf(v0.x); ob.u[1] = f2bf(v0.y); ob.u[2] = f2bf(v0.z); ob.u[3] = f2bf(v0.w);
        ob.u[4] = f2bf(v1.x); ob.u[5] = f2bf(v1.y); ob.u[6] = f2bf(v1.z); ob.u[7] = f2bf(v1.w);
        *(short8v*)&out[(size_t)i * 8] = ob.v;
    }
}

// ---------------- GEMM body: A LDS-dbuf + B LDS-single (49 KB -> 3 blocks/CU) ----------------
// MODE 0/1: LSTM step, N-tile = 32 h x 4 gates (gate-interleaved W rows). MODE 2: proj.
// Tile 128x128, 4 waves, BK=64. LDS: abuf0 16K | abuf1 16K | bbuf 16K. A prefetched one
// tile ahead (dbuf); B staged single-buffered right after the post-compute barrier.
// All A-operand sources are now TIME-MAJOR (row stride = K) -> each gload_lds instr reads
// one contiguous 1KB span (R18 audit: stride Tt*Hh fragmented it into 8 segments).
// vmcnt(4) after stageA(it+1) -> A(it),B(it) complete BEFORE the publishing barrier (R12).
template<int MODE>
__device__ __forceinline__ void step_body(
    bool first, int f, int h0, int b0, int t, int hb, int bb,
    const short* ax, long axs, const short* ah, long ahs,
    const short* __restrict__ wxp, const short* __restrict__ whp,
    const float* __restrict__ bias, unsigned short* __restrict__ cbuf,
    unsigned short* __restrict__ ydst,
    float* __restrict__ part, char* smem)
{
    constexpr int KX = (MODE == 0) ? Ii : Hh;
    constexpr int NX = KX / 64;
    const int NT = (MODE == 2) ? NX : (first ? NX : NX + Hh / 64);

    const int tid = threadIdx.x;
    const int wave = tid >> 6, lane = tid & 63;
    const int wm = (wave >> 1) * 64, wn = (wave & 1) * 64;

    short* sStage = (short*)smem;             // abuf0[0,8192) abuf1[8192,16384) bbuf[16384,24576)
    float* pr = (float*)(smem + 49152);

    f32x4 acc[4][4];
#pragma unroll
    for (int i = 0; i < 4; ++i)
#pragma unroll
        for (int j = 0; j < 4; ++j) acc[i][j] = (f32x4){0.f, 0.f, 0.f, 0.f};

    // staging geometry: per gload_lds instr: 64 lanes x 16B = 1KB = 8 rows of 128B
    const int srow8 = lane >> 3;
    const int csrc  = (lane & 7) ^ srow8;          // pre-swizzled source chunk
    const int frow  = lane & 15, fks = lane >> 4;

    auto stageA = [&](int it, int buf) {
        const short* abase; long as; int kb;
        if (it < NX) { abase = ax; as = axs; kb = it * 64; }
        else         { abase = ah; as = ahs; kb = (it - NX) * 64; }
        short* dA = sStage + buf * 8192;
#pragma unroll
        for (int i = 0; i < 4; ++i) {
            const int inst = wave * 4 + i;
            const int row = inst * 8 + srow8;
            const short* srcA = abase + (size_t)row * as + kb + csrc * 8;
            __builtin_amdgcn_global_load_lds((gas_ptr)(const void*)srcA,
                (las_ptr)(void*)(dA + inst * 512), 16, 0, 0);
        }
    };

    auto stageB = [&](int it) {
        const short* wbase; int K; int kb;
        if (it < NX) { wbase = wxp; K = KX; kb = it * 64; }
        else         { wbase = whp; K = Hh; kb = (it - NX) * 64; }
        short* dB = sStage + 16384;
#pragma unroll
        for (int i = 0; i < 4; ++i) {
            const int inst = wave * 4 + i;
            const int row = inst * 8 + srow8;
            const short* srcB = wbase + (size_t)row * K + kb + csrc * 8;
            __builtin_amdgcn_global_load_lds((gas_ptr)(const void*)srcB,
                (las_ptr)(void*)(dB + inst * 512), 16, 0, 0);
        }
    };

    auto compute = [&](int abuf) {
        const short* bA = sStage + abuf * 8192;
        const short* bB = sStage + 16384;
        __builtin_amdgcn_s_setprio(1);
#pragma unroll
        for (int ks = 0; ks < 2; ++ks) {
            short8v av[4], bv[4];
#pragma unroll
            for (int i = 0; i < 4; ++i) {
                const int r = wm + i * 16 + frow;
                av[i] = *(const short8v*)&bA[r * 64 + (((fks + ks * 4) ^ (r & 7)) * 8)];
            }
#pragma unroll
            for (int j = 0; j < 4; ++j) {
                const int r = wn + j * 16 + frow;
                bv[j] = *(const short8v*)&bB[r * 64 + (((fks + ks * 4) ^ (r & 7)) * 8)];
            }
#pragma unroll
            for (int i = 0; i < 4; ++i)
#pragma unroll
                for (int j = 0; j < 4; ++j)
                    acc[i][j] = __builtin_amdgcn_mfma_f32_16x16x32_bf16(av[i], bv[j], acc[i][j], 0, 0, 0);
        }
        __builtin_amdgcn_s_setprio(0);
    };

    // per-lane output coords and bias (register-local epilogue)
    const int hoff = ((wn >> 6) << 4) + (lane & 15);   // MODE 0/1: h within 32-block
    float bi[4] = {0.f, 0.f, 0.f, 0.f};
    if constexpr (MODE != 2) {
#pragma unroll
        for (int g = 0; g < 4; ++g) bi[g] = bias[(size_t)f * Gg + g * Hh + h0 + hoff];
    } else {
#pragma unroll
        for (int j = 0; j < 4; ++j) bi[j] = bias[h0 + wn + j * 16 + (lane & 15)];
    }
    asm volatile("" : "+v"(bi[0]), "+v"(bi[1]), "+v"(bi[2]), "+v"(bi[3]));

    // -------- pipelined K loop: A 1-tile-ahead dbuf, B single-buf staged post-barrier --------
    stageA(0, 0);
    stageB(0);
    for (int it = 0; it < NT; ++it) {
        if (it + 1 < NT) {
            stageA(it + 1, (it + 1) & 1);
            asm volatile("s_waitcnt vmcnt(4)" ::: "memory");   // A(it), B(it) complete
        } else {
            asm volatile("s_waitcnt vmcnt(0)" ::: "memory");
        }
        __builtin_amdgcn_s_barrier();
        __builtin_amdgcn_sched_barrier(0);
        compute(it & 1);
        __builtin_amdgcn_sched_barrier(0);
        __builtin_amdgcn_s_barrier();
        if (it + 1 < NT) stageB(it + 1);
    }

    // ---- register-local epilogue: gates i,f,g,o live in acc[i][0..3][r] of this lane ----
    if constexpr (MODE != 2) {
#pragma unroll
        for (int i = 0; i < 4; ++i)
#pragma unroll
            for (int r = 0; r < 4; ++r) {
                const int b = b0 + wm + i * 16 + ((lane >> 4) << 2) + r;
                const float gi = acc[i][0][r] + bi[0];
                const float gf = acc[i][1][r] + bi[1];
                const float gg = acc[i][2][r] + bi[2];
                const float go = acc[i][3][r] + bi[3];
                const size_t cidx = ((size_t)f * Bb + b) * Hh + h0 + hoff;
                const float cold = first ? 0.f : bf2f(cbuf[cidx]);
                const float cn = sigmoidf_(gf) * cold + sigmoidf_(gi) * tanhf_(gg);
                const float hv = sigmoidf_(go) * tanhf_(cn);
                cbuf[cidx] = f2bf(cn);
                const unsigned short hb2 = f2bf(hv);
                if (MODE == 0)
                    ydst[(((size_t)f * Tt + t) * Bb + b) * Hh + h0 + hoff] = hb2;   // [f][t][b][h]
                else
                    ydst[cidx] = hb2;
            }
    } else {
        float ssum = 0.f, ssq = 0.f;
#pragma unroll
        for (int i = 0; i < 4; ++i)
#pragma unroll
            for (int r = 0; r < 4; ++r) {
                const int b = b0 + wm + i * 16 + ((lane >> 4) << 2) + r;
                unsigned short* dst = ydst + (((size_t)f * Tt + t) * Bb + b) * Hh;   // [f][t][b][h]
#pragma unroll
                for (int j = 0; j < 4; ++j) {
                    const int o = h0 + wn + j * 16 + (lane & 15);
                    const unsigned short hb2 = f2bf(acc[i][j][r] + bi[j]);
                    const float hv = bf2f(hb2);
                    ssum += hv; ssq += hv * hv;
                    dst[o] = hb2;
                }
            }
#pragma unroll
        for (int off2 = 32; off2 > 0; off2 >>= 1) {
            ssum += __shfl_down(ssum, off2);
            ssq  += __shfl_down(ssq,  off2);
        }
        if (lane == 0) { pr[wave * 2] = ssum; pr[wave * 2 + 1] = ssq; }
        __syncthreads();
        if (tid == 0) {
            float S = 0.f, Q = 0.f;
#pragma unroll
            for (int w = 0; w < 4; ++w) { S += pr[w * 2]; Q += pr[w * 2 + 1]; }
            const size_t pi = (((size_t)f * Tt + t) * 4 + hb) * 8 + bb;
            part[pi * 2] = S; part[pi * 2 + 1] = Q;
        }
    }
}

// ---------------- merged per-step kernel: L0(t=d) | L1(t=d-1) | proj(t=d-2) ----------------
// grid = (Ff, 16, 18) — R17 dispatch order (hb-blocks sharing an A-tile stay adjacent).
// Xbf is [t][b][i]; ybuf is [f][t][b][h] -> every A source has row stride = K (contiguous
// 1KB per staging instr). All cross-role deps span a dispatch boundary -> race-free.
__global__ __launch_bounds__(256, 3) void step_merged(
    const short* __restrict__ Xbf, short* __restrict__ ybuf,
    short* __restrict__ h1A, short* __restrict__ h1B,
    const short* __restrict__ W0x, const short* __restrict__ W0h,
    const short* __restrict__ W1x, const short* __restrict__ W1h,
    const short* __restrict__ A1bf,
    const float* __restrict__ b0p, const float* __restrict__ b1p,
    const float* __restrict__ c1v,
    unsigned short* __restrict__ c0buf, unsigned short* __restrict__ c1buf,
    float* __restrict__ part, int d)
{
    __shared__ __align__(16) char smem[49152 + 64];
    const int f = blockIdx.x;
    const int zz = blockIdx.z;

    if (zz < 8) {                       // ---- layer 0, t = d ----
        const int t = d;
        if (t >= Tt) return;
        const int hb = blockIdx.y, h0 = hb * 32, b0 = zz * 128;
        const bool first = (t == 0);
        const short* ax = Xbf + ((size_t)t * Bb + b0) * Ii;
        const short* ah = first ? nullptr
                                : ybuf + (((size_t)f * Tt + (t - 1)) * Bb + b0) * Hh;
        step_body<0>(first, f, h0, b0, t, hb, zz,
                     ax, (long)Ii, ah, (long)Hh,
                     W0x + ((size_t)f * 16 + hb) * 128 * Ii,
                     W0h + ((size_t)f * 16 + hb) * 128 * Hh,
                     b0p, c0buf, (unsigned short*)ybuf, part, smem);
    } else if (zz < 16) {               // ---- layer 1, t = d-1 ----
        const int t = d - 1;
        if (t < 0 || t >= Tt) return;
        const int bb = zz - 8;
        const int hb = blockIdx.y, h0 = hb * 32, b0 = bb * 128;
        const bool first = (t == 0);
        short* hn = (t & 1) ? h1A : h1B;
        const short* hp = (t & 1) ? h1B : h1A;
        const short* ax = ybuf + (((size_t)f * Tt + t) * Bb + b0) * Hh;
        const short* ah = first ? nullptr : hp + ((size_t)f * Bb + b0) * Hh;
        step_body<1>(first, f, h0, b0, t, hb, bb,
                     ax, (long)Hh, ah, (long)Hh,
                     W1x + ((size_t)f * 16 + hb) * 128 * Hh,
                     W1h + ((size_t)f * 16 + hb) * 128 * Hh,
                     b1p, c1buf, (unsigned short*)hn, part, smem);
    } else {                            // ---- proj, t = d-2 ----
        const int t = d - 2;
        if (t < 0) return;
        const int hb = blockIdx.y & 3, h0 = hb * 128;
        const int bb = (zz - 16) * 4 + (blockIdx.y >> 2), b0 = bb * 128;
        const short* hn = (t & 1) ? h1A : h1B;
        const short* ax = hn + ((size_t)f * Bb + b0) * Hh;
        step_body<2>(false, f, h0, b0, t, hb, bb,
                     ax, (long)Hh, nullptr, 0L,
                     A1bf + (size_t)h0 * Hh, nullptr,
                     c1v, nullptr, (unsigned short*)ybuf, part, smem);
    }
}

// ---------------- stats combine: mean / rsqrt(var) per (f,t) from 32 partials ----------------
__global__ void stats_combine_kernel(const float* __restrict__ part, float* __restrict__ stats)
{
    const int i = threadIdx.x;
    if (i < Ff * Tt) {
        float s = 0.f, q = 0.f;
        for (int j = 0; j < 32; ++j) { s += part[(i * 32 + j) * 2]; q += part[(i * 32 + j) * 2 + 1]; }
        const float n = (float)((size_t)Bb * Hh);
        const float mean = s / n;
        const float var  = q / n - mean * mean;
        stats[i * 2]     = mean;
        stats[i * 2 + 1] = rsqrtf(var + 1e-5f);
    }
}

// ---------------- Output: out[b,t,f] = sum_o relu(bn(htmp)) * A2[o] + c2 ----------------
// htmp layout [f][t][b][h]: row = (f*Tt+t)*Bb + b.
__global__ __launch_bounds__(256) void out_kernel(
    const unsigned short* __restrict__ htmp, const float* __restrict__ stats,
    const float* __restrict__ gamma, const float* __restrict__ beta,
    const float* __restrict__ A2, const float* __restrict__ c2,
    float* __restrict__ out)
{
    const int wave = threadIdx.x >> 6;
    const int lane = threadIdx.x & 63;
    const size_t row = (size_t)blockIdx.x * 4 + wave;   // (f*Tt + t)*Bb + b
    const int b = (int)(row % Bb);
    const size_t ft = row / Bb;
    const int t = (int)(ft % Tt);
    const int f = (int)(ft / Tt);

    const float mean = stats[(f * Tt + t) * 2];
    const float inv  = stats[(f * Tt + t) * 2 + 1];
    const float ga = gamma[t], be = beta[t];
    const unsigned short* hrow = htmp + row * Hh;

    union { float4 f4; unsigned short u[8]; } hv;
    hv.f4 = *(const float4*)(hrow + lane * 8);
    const float4 a0 = *(const float4*)(A2 + lane * 8);
    const float4 a1 = *(const float4*)(A2 + lane * 8 + 4);
    const float a2v[8] = {a0.x, a0.y, a0.z, a0.w, a1.x, a1.y, a1.z, a1.w};

    float acc = 0.f;
#pragma unroll
    for (int j = 0; j < 8; ++j) {
        const float x = (bf2f(hv.u[j]) - mean) * inv * ga + be;
        acc += fmaxf(x, 0.f) * a2v[j];
    }
#pragma unroll
    for (int off = 32; off > 0; off >>= 1) acc += __shfl_down(acc, off);
    if (lane == 0) out[(size_t)b * Tt * Ff + (size_t)t * Ff + f] = acc + c2[0];
}

extern "C" void kernel_launch(void* const* d_in, const int* in_sizes, int n_in,
                              void* d_out, int out_size, void* d_ws, size_t ws_size,
                              hipStream_t stream) {
    const float* X     = (const float*)d_in[0];
    const float* Wih0  = (const float*)d_in[1];
    const float* Whh0  = (const float*)d_in[2];
    const float* b0p   = (const float*)d_in[3];
    const float* Wih1  = (const float*)d_in[4];
    const float* Whh1  = (const float*)d_in[5];
    const float* b1p   = (const float*)d_in[6];
    const float* A1    = (const float*)d_in[7];
    const float* c1v   = (const float*)d_in[8];
    const float* gamma = (const float*)d_in[9];
    const float* beta  = (const float*)d_in[10];
    const float* A2    = (const float*)d_in[11];
    const float* c2    = (const float*)d_in[12];
    float* out = (float*)d_out;

    // ---- workspace layout (bytes), total ~209 MiB ----
    char* ws = (char*)d_ws;
    size_t off = 0;
    short* Xbf    = (short*)(ws + off); off += (size_t)Bb * Tt * Ii * 2;       // [t][b][i]
    short* Wih0bf = (short*)(ws + off); off += (size_t)Ff * Gg * Ii * 2;
    short* Whh0bf = (short*)(ws + off); off += (size_t)Ff * Gg * Hh * 2;
    short* Wih1bf = (short*)(ws + off); off += (size_t)Ff * Gg * Hh * 2;
    short* Whh1bf = (short*)(ws + off); off += (size_t)Ff * Gg * Hh * 2;
    short* A1bf   = (short*)(ws + off); off += (size_t)Hh * Hh * 2;
    short* ybuf   = (short*)(ws + off); off += (size_t)Ff * Bb * Tt * Hh * 2;  // [f][t][b][h]
    short* h1A    = (short*)(ws + off); off += (size_t)Ff * Bb * Hh * 2;
    short* h1B    = (short*)(ws + off); off += (size_t)Ff * Bb * Hh * 2;
    unsigned short* c0buf = (unsigned short*)(ws + off); off += (size_t)Ff * Bb * Hh * 2;
    unsigned short* c1buf = (unsigned short*)(ws + off); off += (size_t)Ff * Bb * Hh * 2;
    float* part   = (float*)(ws + off); off += (size_t)Ff * Tt * 32 * 2 * 4;
    float* stats  = (float*)(ws + off); off += (size_t)Ff * Tt * 2 * 4;

    const dim3 blk(256);
    cvt_xT_kernel<<<dim3((Bb * Tt * Ii / 8 + 255) / 256), blk, 0, stream>>>(X, (unsigned short*)Xbf);
    // weights: gate-interleaved permuted layout [f][hb][128][K]
    cvt_wperm_kernel<<<dim3((Ff * Gg * Ii / 8 + 255) / 256), blk, 0, stream>>>(
        Wih0, (unsigned short*)Wih0bf, Ii / 8, Ff * Gg * Ii / 8);
    cvt_wperm_kernel<<<dim3((Ff * Gg * Hh / 8 + 255) / 256), blk, 0, stream>>>(
        Whh0, (unsigned short*)Whh0bf, Hh / 8, Ff * Gg * Hh / 8);
    cvt_wperm_kernel<<<dim3((Ff * Gg * Hh / 8 + 255) / 256), blk, 0, stream>>>(
        Wih1, (unsigned short*)Wih1bf, Hh / 8, Ff * Gg * Hh / 8);
    cvt_wperm_kernel<<<dim3((Ff * Gg * Hh / 8 + 255) / 256), blk, 0, stream>>>(
        Whh1, (unsigned short*)Whh1bf, Hh / 8, Ff * Gg * Hh / 8);
    cvt_kernel<<<dim3((Hh * Hh / 8 + 255) / 256), blk, 0, stream>>>(A1, (unsigned short*)A1bf, Hh * Hh / 8);

    // software-pipelined role-merged steps: d=0..16
    const dim3 gmerged(Ff, 16, 18);
    for (int d = 0; d <= Tt + 1; ++d) {
        step_merged<<<gmerged, blk, 0, stream>>>(
            Xbf, ybuf, h1A, h1B,
            Wih0bf, Whh0bf, Wih1bf, Whh1bf, A1bf,
            b0p, b1p, c1v, c0buf, c1buf, part, d);
    }

    stats_combine_kernel<<<dim3(1), dim3(128), 0, stream>>>(part, stats);
    out_kernel<<<dim3(Ff * Bb * Tt / 4), blk, 0, stream>>>((const unsigned short*)ybuf, stats,
        gamma, beta, A2, c2, out);
    (void)in_sizes; (void)n_in; (void)out_size; (void)ws_size;
}

// Round 20
// 1224.172 us; speedup vs baseline: 1.0577x; 1.0092x over previous
//
#include <hip/hip_runtime.h>
#include <hip/hip_bf16.h>
#include <math.h>

#define Bb 1024
#define Tt 15
#define Ii 256
#define Hh 512
#define Ff 8
#define Gg 2048  // 4*Hh

// fused-convert region sizes (in 8-element chunks)
#define NCX  (Bb * Tt * Ii / 8)     // 491,520  X transpose
#define NW0X (Ff * Gg * Ii / 8)     // 524,288  Wih0 perm (Kc=32)
#define NWH  (Ff * Gg * Hh / 8)     // 1,048,576 Whh0/Wih1/Whh1 perm (Kc=64)
#define NA1  (Hh * Hh / 8)          // 32,768   A1 plain
#define NTOT (NCX + NW0X + 3 * NWH + NA1)   // 4,194,304

typedef __attribute__((ext_vector_type(8))) short short8v;
typedef __attribute__((ext_vector_type(4))) float f32x4;

typedef const __attribute__((address_space(1))) void* gas_ptr;
typedef __attribute__((address_space(3))) void* las_ptr;

__device__ __forceinline__ float sigmoidf_(float x) {
    return __builtin_amdgcn_rcpf(1.0f + __expf(-x));
}
__device__ __forceinline__ float tanhf_(float x) {
    x = fminf(fmaxf(x, -15.0f), 15.0f);
    const float e = __expf(2.0f * x);
    return (e - 1.0f) * __builtin_amdgcn_rcpf(e + 1.0f);
}
__device__ __forceinline__ float bf2f(unsigned short u) {
    return __uint_as_float(((unsigned int)u) << 16);
}
__device__ __forceinline__ unsigned short f2bf(float f) {
    unsigned int u = __float_as_uint(f);
    u += 0x7fffu + ((u >> 16) & 1u);   // RNE
    return (unsigned short)(u >> 16);
}

__device__ __forceinline__ short8v cvt8(const float* __restrict__ in, size_t elem) {
    const float4 v0 = *(const float4*)(in + elem);
    const float4 v1 = *(const float4*)(in + elem + 4);
    union { unsigned short u[8]; short8v v; } ob;
    ob.u[0] = f2bf(v0.x); ob.u[1] = f2bf(v0.y); ob.u[2] = f2bf(v0.z); ob.u[3] = f2bf(v0.w);
    ob.u[4] = f2bf(v1.x); ob.u[5] = f2bf(v1.y); ob.u[6] = f2bf(v1.z); ob.u[7] = f2bf(v1.w);
    return ob.v;
}

// gate-interleaved row permutation: out[f][hb][r][K], r=0..127: gate=(r>>4)&3,
// hl=(r&15)+((r>>6)<<4); src row = f*Gg + gate*Hh + hb*32 + hl.
__device__ __forceinline__ void wperm1(const float* __restrict__ in,
                                       unsigned short* __restrict__ out, int Kc, int i) {
    const int k8 = i % Kc;
    const int r  = (i / Kc) & 127;
    const int hb = (i / (Kc * 128)) & 15;
    const int f  = i / (Kc * 128 * 16);
    const int gate = (r >> 4) & 3;
    const int hl = (r & 15) + ((r >> 6) << 4);
    const size_t src = ((size_t)f * Gg + gate * Hh + hb * 32 + hl) * (size_t)(Kc * 8) + k8 * 8;
    *(short8v*)&out[(size_t)i * 8] = cvt8(in, src);
}

// ---------------- fused prologue: all fp32->bf16 converts in ONE dispatch ----------------
__global__ __launch_bounds__(256) void cvt_all_kernel(
    const float* __restrict__ X,    const float* __restrict__ Wih0,
    const float* __restrict__ Whh0, const float* __restrict__ Wih1,
    const float* __restrict__ Whh1, const float* __restrict__ A1,
    unsigned short* __restrict__ Xbf, unsigned short* __restrict__ W0x,
    unsigned short* __restrict__ W0h, unsigned short* __restrict__ W1x,
    unsigned short* __restrict__ W1h, unsigned short* __restrict__ A1bf)
{
    const int i = blockIdx.x * 256 + threadIdx.x;
    if (i < NCX) {
        // X: [b][t][i] fp32 -> [t][b][i] bf16 (time-major)
        const int c = i % (Ii / 8);
        const int rest = i / (Ii / 8);
        const int t = rest % Tt;
        const int b = rest / Tt;
        *(short8v*)&Xbf[((size_t)(t * Bb + b) * (Ii / 8) + c) * 8] =
            cvt8(X, ((size_t)(b * Tt + t) * (Ii / 8) + c) * 8);
    } else if (i < NCX + NW0X) {
        wperm1(Wih0, W0x, Ii / 8, i - NCX);
    } else if (i < NCX + NW0X + NWH) {
        wperm1(Whh0, W0h, Hh / 8, i - NCX - NW0X);
    } else if (i < NCX + NW0X + 2 * NWH) {
        wperm1(Wih1, W1x, Hh / 8, i - NCX - NW0X - NWH);
    } else if (i < NCX + NW0X + 3 * NWH) {
        wperm1(Whh1, W1h, Hh / 8, i - NCX - NW0X - 2 * NWH);
    } else {
        const int j = i - (NCX + NW0X + 3 * NWH);
        *(short8v*)&A1bf[(size_t)j * 8] = cvt8(A1, (size_t)j * 8);
    }
}

// ---------------- GEMM body: A LDS-dbuf + B LDS-single (49 KB -> 3 blocks/CU) ----------------
// MODE 0/1: LSTM step, N-tile = 32 h x 4 gates (gate-interleaved W rows). MODE 2: proj.
// Tile 128x128, 4 waves, BK=64. LDS: abuf0 16K | abuf1 16K | bbuf 16K. A prefetched one
// tile ahead (dbuf); B staged single-buffered right after the post-compute barrier.
// All A sources are time-major (row stride = K): one contiguous 1KB span per staging instr.
// vmcnt(4) after stageA(it+1) -> A(it),B(it) complete BEFORE the publishing barrier (R12).
template<int MODE>
__device__ __forceinline__ void step_body(
    bool first, int f, int h0, int b0, int t, int hb, int bb,
    const short* ax, long axs, const short* ah, long ahs,
    const short* __restrict__ wxp, const short* __restrict__ whp,
    const float* __restrict__ bias, unsigned short* __restrict__ cbuf,
    unsigned short* __restrict__ ydst,
    float* __restrict__ part, char* smem)
{
    constexpr int KX = (MODE == 0) ? Ii : Hh;
    constexpr int NX = KX / 64;
    const int NT = (MODE == 2) ? NX : (first ? NX : NX + Hh / 64);

    const int tid = threadIdx.x;
    const int wave = tid >> 6, lane = tid & 63;
    const int wm = (wave >> 1) * 64, wn = (wave & 1) * 64;

    short* sStage = (short*)smem;             // abuf0[0,8192) abuf1[8192,16384) bbuf[16384,24576)
    float* pr = (float*)(smem + 49152);

    f32x4 acc[4][4];
#pragma unroll
    for (int i = 0; i < 4; ++i)
#pragma unroll
        for (int j = 0; j < 4; ++j) acc[i][j] = (f32x4){0.f, 0.f, 0.f, 0.f};

    // staging geometry: per gload_lds instr: 64 lanes x 16B = 1KB = 8 rows of 128B
    const int srow8 = lane >> 3;
    const int csrc  = (lane & 7) ^ srow8;          // pre-swizzled source chunk
    const int frow  = lane & 15, fks = lane >> 4;

    auto stageA = [&](int it, int buf) {
        const short* abase; long as; int kb;
        if (it < NX) { abase = ax; as = axs; kb = it * 64; }
        else         { abase = ah; as = ahs; kb = (it - NX) * 64; }
        short* dA = sStage + buf * 8192;
#pragma unroll
        for (int i = 0; i < 4; ++i) {
            const int inst = wave * 4 + i;
            const int row = inst * 8 + srow8;
            const short* srcA = abase + (size_t)row * as + kb + csrc * 8;
            __builtin_amdgcn_global_load_lds((gas_ptr)(const void*)srcA,
                (las_ptr)(void*)(dA + inst * 512), 16, 0, 0);
        }
    };

    auto stageB = [&](int it) {
        const short* wbase; int K; int kb;
        if (it < NX) { wbase = wxp; K = KX; kb = it * 64; }
        else         { wbase = whp; K = Hh; kb = (it - NX) * 64; }
        short* dB = sStage + 16384;
#pragma unroll
        for (int i = 0; i < 4; ++i) {
            const int inst = wave * 4 + i;
            const int row = inst * 8 + srow8;
            const short* srcB = wbase + (size_t)row * K + kb + csrc * 8;
            __builtin_amdgcn_global_load_lds((gas_ptr)(const void*)srcB,
                (las_ptr)(void*)(dB + inst * 512), 16, 0, 0);
        }
    };

    auto compute = [&](int abuf) {
        const short* bA = sStage + abuf * 8192;
        const short* bB = sStage + 16384;
        __builtin_amdgcn_s_setprio(1);
#pragma unroll
        for (int ks = 0; ks < 2; ++ks) {
            short8v av[4], bv[4];
#pragma unroll
            for (int i = 0; i < 4; ++i) {
                const int r = wm + i * 16 + frow;
                av[i] = *(const short8v*)&bA[r * 64 + (((fks + ks * 4) ^ (r & 7)) * 8)];
            }
#pragma unroll
            for (int j = 0; j < 4; ++j) {
                const int r = wn + j * 16 + frow;
                bv[j] = *(const short8v*)&bB[r * 64 + (((fks + ks * 4) ^ (r & 7)) * 8)];
            }
#pragma unroll
            for (int i = 0; i < 4; ++i)
#pragma unroll
                for (int j = 0; j < 4; ++j)
                    acc[i][j] = __builtin_amdgcn_mfma_f32_16x16x32_bf16(av[i], bv[j], acc[i][j], 0, 0, 0);
        }
        __builtin_amdgcn_s_setprio(0);
    };

    // per-lane output coords and bias (register-local epilogue)
    const int hoff = ((wn >> 6) << 4) + (lane & 15);   // MODE 0/1: h within 32-block
    float bi[4] = {0.f, 0.f, 0.f, 0.f};
    if constexpr (MODE != 2) {
#pragma unroll
        for (int g = 0; g < 4; ++g) bi[g] = bias[(size_t)f * Gg + g * Hh + h0 + hoff];
    } else {
#pragma unroll
        for (int j = 0; j < 4; ++j) bi[j] = bias[h0 + wn + j * 16 + (lane & 15)];
    }
    asm volatile("" : "+v"(bi[0]), "+v"(bi[1]), "+v"(bi[2]), "+v"(bi[3]));

    // -------- pipelined K loop: A 1-tile-ahead dbuf, B single-buf staged post-barrier --------
    stageA(0, 0);
    stageB(0);
    for (int it = 0; it < NT; ++it) {
        if (it + 1 < NT) {
            stageA(it + 1, (it + 1) & 1);
            asm volatile("s_waitcnt vmcnt(4)" ::: "memory");   // A(it), B(it) complete
        } else {
            asm volatile("s_waitcnt vmcnt(0)" ::: "memory");
        }
        __builtin_amdgcn_s_barrier();
        __builtin_amdgcn_sched_barrier(0);
        compute(it & 1);
        __builtin_amdgcn_sched_barrier(0);
        __builtin_amdgcn_s_barrier();
        if (it + 1 < NT) stageB(it + 1);
    }

    // ---- register-local epilogue: gates i,f,g,o live in acc[i][0..3][r] of this lane ----
    if constexpr (MODE != 2) {
#pragma unroll
        for (int i = 0; i < 4; ++i)
#pragma unroll
            for (int r = 0; r < 4; ++r) {
                const int b = b0 + wm + i * 16 + ((lane >> 4) << 2) + r;
                const float gi = acc[i][0][r] + bi[0];
                const float gf = acc[i][1][r] + bi[1];
                const float gg = acc[i][2][r] + bi[2];
                const float go = acc[i][3][r] + bi[3];
                const size_t cidx = ((size_t)f * Bb + b) * Hh + h0 + hoff;
                const float cold = first ? 0.f : bf2f(cbuf[cidx]);
                const float cn = sigmoidf_(gf) * cold + sigmoidf_(gi) * tanhf_(gg);
                const float hv = sigmoidf_(go) * tanhf_(cn);
                cbuf[cidx] = f2bf(cn);
                const unsigned short hb2 = f2bf(hv);
                if (MODE == 0)
                    ydst[(((size_t)f * Tt + t) * Bb + b) * Hh + h0 + hoff] = hb2;   // [f][t][b][h]
                else
                    ydst[cidx] = hb2;
            }
    } else {
        float ssum = 0.f, ssq = 0.f;
#pragma unroll
        for (int i = 0; i < 4; ++i)
#pragma unroll
            for (int r = 0; r < 4; ++r) {
                const int b = b0 + wm + i * 16 + ((lane >> 4) << 2) + r;
                unsigned short* dst = ydst + (((size_t)f * Tt + t) * Bb + b) * Hh;   // [f][t][b][h]
#pragma unroll
                for (int j = 0; j < 4; ++j) {
                    const int o = h0 + wn + j * 16 + (lane & 15);
                    const unsigned short hb2 = f2bf(acc[i][j][r] + bi[j]);
                    const float hv = bf2f(hb2);
                    ssum += hv; ssq += hv * hv;
                    dst[o] = hb2;
                }
            }
#pragma unroll
        for (int off2 = 32; off2 > 0; off2 >>= 1) {
            ssum += __shfl_down(ssum, off2);
            ssq  += __shfl_down(ssq,  off2);
        }
        if (lane == 0) { pr[wave * 2] = ssum; pr[wave * 2 + 1] = ssq; }
        __syncthreads();
        if (tid == 0) {
            float S = 0.f, Q = 0.f;
#pragma unroll
            for (int w = 0; w < 4; ++w) { S += pr[w * 2]; Q += pr[w * 2 + 1]; }
            const size_t pi = (((size_t)f * Tt + t) * 4 + hb) * 8 + bb;
            part[pi * 2] = S; part[pi * 2 + 1] = Q;
        }
    }
}

// ---------------- merged per-step kernel: L0(t=d) | L1(t=d-1) | proj(t=d-2) ----------------
// grid = (Ff, 16, 18) — R17 dispatch order (hb-blocks sharing an A-tile stay adjacent).
// Xbf is [t][b][i]; ybuf is [f][t][b][h]. All cross-role deps span a dispatch boundary.
__global__ __launch_bounds__(256, 3) void step_merged(
    const short* __restrict__ Xbf, short* __restrict__ ybuf,
    short* __restrict__ h1A, short* __restrict__ h1B,
    const short* __restrict__ W0x, const short* __restrict__ W0h,
    const short* __restrict__ W1x, const short* __restrict__ W1h,
    const short* __restrict__ A1bf,
    const float* __restrict__ b0p, const float* __restrict__ b1p,
    const float* __restrict__ c1v,
    unsigned short* __restrict__ c0buf, unsigned short* __restrict__ c1buf,
    float* __restrict__ part, int d)
{
    __shared__ __align__(16) char smem[49152 + 64];
    const int f = blockIdx.x;
    const int zz = blockIdx.z;

    if (zz < 8) {                       // ---- layer 0, t = d ----
        const int t = d;
        if (t >= Tt) return;
        const int hb = blockIdx.y, h0 = hb * 32, b0 = zz * 128;
        const bool first = (t == 0);
        const short* ax = Xbf + ((size_t)t * Bb + b0) * Ii;
        const short* ah = first ? nullptr
                                : ybuf + (((size_t)f * Tt + (t - 1)) * Bb + b0) * Hh;
        step_body<0>(first, f, h0, b0, t, hb, zz,
                     ax, (long)Ii, ah, (long)Hh,
                     W0x + ((size_t)f * 16 + hb) * 128 * Ii,
                     W0h + ((size_t)f * 16 + hb) * 128 * Hh,
                     b0p, c0buf, (unsigned short*)ybuf, part, smem);
    } else if (zz < 16) {               // ---- layer 1, t = d-1 ----
        const int t = d - 1;
        if (t < 0 || t >= Tt) return;
        const int bb = zz - 8;
        const int hb = blockIdx.y, h0 = hb * 32, b0 = bb * 128;
        const bool first = (t == 0);
        short* hn = (t & 1) ? h1A : h1B;
        const short* hp = (t & 1) ? h1B : h1A;
        const short* ax = ybuf + (((size_t)f * Tt + t) * Bb + b0) * Hh;
        const short* ah = first ? nullptr : hp + ((size_t)f * Bb + b0) * Hh;
        step_body<1>(first, f, h0, b0, t, hb, bb,
                     ax, (long)Hh, ah, (long)Hh,
                     W1x + ((size_t)f * 16 + hb) * 128 * Hh,
                     W1h + ((size_t)f * 16 + hb) * 128 * Hh,
                     b1p, c1buf, (unsigned short*)hn, part, smem);
    } else {                            // ---- proj, t = d-2 ----
        const int t = d - 2;
        if (t < 0) return;
        const int hb = blockIdx.y & 3, h0 = hb * 128;
        const int bb = (zz - 16) * 4 + (blockIdx.y >> 2), b0 = bb * 128;
        const short* hn = (t & 1) ? h1A : h1B;
        const short* ax = hn + ((size_t)f * Bb + b0) * Hh;
        step_body<2>(false, f, h0, b0, t, hb, bb,
                     ax, (long)Hh, nullptr, 0L,
                     A1bf + (size_t)h0 * Hh, nullptr,
                     c1v, nullptr, (unsigned short*)ybuf, part, smem);
    }
}

// ---------------- stats combine: mean / rsqrt(var) per (f,t) from 32 partials ----------------
__global__ void stats_combine_kernel(const float* __restrict__ part, float* __restrict__ stats)
{
    const int i = threadIdx.x;
    if (i < Ff * Tt) {
        float s = 0.f, q = 0.f;
        for (int j = 0; j < 32; ++j) { s += part[(i * 32 + j) * 2]; q += part[(i * 32 + j) * 2 + 1]; }
        const float n = (float)((size_t)Bb * Hh);
        const float mean = s / n;
        const float var  = q / n - mean * mean;
        stats[i * 2]     = mean;
        stats[i * 2 + 1] = rsqrtf(var + 1e-5f);
    }
}

// ---------------- Output: out[b,t,f] = sum_o relu(bn(htmp)) * A2[o] + c2 ----------------
// htmp layout [f][t][b][h]: row = (f*Tt+t)*Bb + b.
__global__ __launch_bounds__(256) void out_kernel(
    const unsigned short* __restrict__ htmp, const float* __restrict__ stats,
    const float* __restrict__ gamma, const float* __restrict__ beta,
    const float* __restrict__ A2, const float* __restrict__ c2,
    float* __restrict__ out)
{
    const int wave = threadIdx.x >> 6;
    const int lane = threadIdx.x & 63;
    const size_t row = (size_t)blockIdx.x * 4 + wave;   // (f*Tt + t)*Bb + b
    const int b = (int)(row % Bb);
    const size_t ft = row / Bb;
    const int t = (int)(ft % Tt);
    const int f = (int)(ft / Tt);

    const float mean = stats[(f * Tt + t) * 2];
    const float inv  = stats[(f * Tt + t) * 2 + 1];
    const float ga = gamma[t], be = beta[t];
    const unsigned short* hrow = htmp + row * Hh;

    union { float4 f4; unsigned short u[8]; } hv;
    hv.f4 = *(const float4*)(hrow + lane * 8);
    const float4 a0 = *(const float4*)(A2 + lane * 8);
    const float4 a1 = *(const float4*)(A2 + lane * 8 + 4);
    const float a2v[8] = {a0.x, a0.y, a0.z, a0.w, a1.x, a1.y, a1.z, a1.w};

    float acc = 0.f;
#pragma unroll
    for (int j = 0; j < 8; ++j) {
        const float x = (bf2f(hv.u[j]) - mean) * inv * ga + be;
        acc += fmaxf(x, 0.f) * a2v[j];
    }
#pragma unroll
    for (int off = 32; off > 0; off >>= 1) acc += __shfl_down(acc, off);
    if (lane == 0) out[(size_t)b * Tt * Ff + (size_t)t * Ff + f] = acc + c2[0];
}

extern "C" void kernel_launch(void* const* d_in, const int* in_sizes, int n_in,
                              void* d_out, int out_size, void* d_ws, size_t ws_size,
                              hipStream_t stream) {
    const float* X     = (const float*)d_in[0];
    const float* Wih0  = (const float*)d_in[1];
    const float* Whh0  = (const float*)d_in[2];
    const float* b0p   = (const float*)d_in[3];
    const float* Wih1  = (const float*)d_in[4];
    const float* Whh1  = (const float*)d_in[5];
    const float* b1p   = (const float*)d_in[6];
    const float* A1    = (const float*)d_in[7];
    const float* c1v   = (const float*)d_in[8];
    const float* gamma = (const float*)d_in[9];
    const float* beta  = (const float*)d_in[10];
    const float* A2    = (const float*)d_in[11];
    const float* c2    = (const float*)d_in[12];
    float* out = (float*)d_out;

    // ---- workspace layout (bytes), total ~209 MiB ----
    char* ws = (char*)d_ws;
    size_t off = 0;
    short* Xbf    = (short*)(ws + off); off += (size_t)Bb * Tt * Ii * 2;       // [t][b][i]
    short* Wih0bf = (short*)(ws + off); off += (size_t)Ff * Gg * Ii * 2;
    short* Whh0bf = (short*)(ws + off); off += (size_t)Ff * Gg * Hh * 2;
    short* Wih1bf = (short*)(ws + off); off += (size_t)Ff * Gg * Hh * 2;
    short* Whh1bf = (short*)(ws + off); off += (size_t)Ff * Gg * Hh * 2;
    short* A1bf   = (short*)(ws + off); off += (size_t)Hh * Hh * 2;
    short* ybuf   = (short*)(ws + off); off += (size_t)Ff * Bb * Tt * Hh * 2;  // [f][t][b][h]
    short* h1A    = (short*)(ws + off); off += (size_t)Ff * Bb * Hh * 2;
    short* h1B    = (short*)(ws + off); off += (size_t)Ff * Bb * Hh * 2;
    unsigned short* c0buf = (unsigned short*)(ws + off); off += (size_t)Ff * Bb * Hh * 2;
    unsigned short* c1buf = (unsigned short*)(ws + off); off += (size_t)Ff * Bb * Hh * 2;
    float* part   = (float*)(ws + off); off += (size_t)Ff * Tt * 32 * 2 * 4;
    float* stats  = (float*)(ws + off); off += (size_t)Ff * Tt * 2 * 4;

    const dim3 blk(256);
    // fused prologue: all converts (X transpose + 4 weight perms + A1) in one dispatch
    cvt_all_kernel<<<dim3(NTOT / 256), blk, 0, stream>>>(
        X, Wih0, Whh0, Wih1, Whh1, A1,
        (unsigned short*)Xbf, (unsigned short*)Wih0bf, (unsigned short*)Whh0bf,
        (unsigned short*)Wih1bf, (unsigned short*)Whh1bf, (unsigned short*)A1bf);

    // software-pipelined role-merged steps: d=0..16
    const dim3 gmerged(Ff, 16, 18);
    for (int d = 0; d <= Tt + 1; ++d) {
        step_merged<<<gmerged, blk, 0, stream>>>(
            Xbf, ybuf, h1A, h1B,
            Wih0bf, Whh0bf, Wih1bf, Whh1bf, A1bf,
            b0p, b1p, c1v, c0buf, c1buf, part, d);
    }

    stats_combine_kernel<<<dim3(1), dim3(128), 0, stream>>>(part, stats);
    out_kernel<<<dim3(Ff * Bb * Tt / 4), blk, 0, stream>>>((const unsigned short*)ybuf, stats,
        gamma, beta, A2, c2, out);
    (void)in_sizes; (void)n_in; (void)out_size; (void)ws_size;
}